// Round 4
// baseline (221.069 us; speedup 1.0000x reference)
//
#include <hip/hip_runtime.h>
#include <math.h>

#define CCH 512
#define F1 25088      // 512*49
#define FC 4096
#define NCLS 1000
#define OW 224
#define KSPLIT 4
#define KSLICE 1024   // FC/KSPLIT
#define TJ 32         // j-tile of fused GEMM
#define PSTRIDE (CCH*FC)

// ws float offsets
#define WS_DT 0                         // [4096][512]
#define WS_MP (WS_DT + FC*CCH)          // 25088
#define WS_QS (WS_MP + F1)              // [4096][8] eighth sums
#define WS_H1PRE (WS_QS + FC*8)         // 4096
#define WS_H1 (WS_H1PRE + FC)           // 4096
#define WS_H2 (WS_H1 + FC)              // 4096
#define WS_H2PART (WS_H2 + FC)          // [4][4096]
#define WS_LOGITS (WS_H2PART + 4*FC)    // 1000
#define WS_CLSBASE (WS_LOGITS + NCLS)   // 2
#define WS_ALPHA (WS_CLSBASE + 2)       // 512
#define WS_MINMAX (WS_ALPHA + CCH)      // 2 ints
#define WS_WEIGHTED (WS_MINMAX + 2)     // 196
#define WS_LOGPART (WS_WEIGHTED + 196)  // [64][512] (fallback)
#define WS_A (WS_LOGPART + 64*CCH)      // bf16 [512][4096]
#define WS_PART (WS_A + CCH*FC/2)       // f32 [4][512][4096]
#define WS_END (WS_PART + KSPLIT*CCH*FC)
#define WS_NEED_BYTES ((size_t)WS_END * 4)

typedef __attribute__((ext_vector_type(8))) short bfrag;
typedef __attribute__((ext_vector_type(4))) float f32x4;

static __device__ __forceinline__ unsigned short f2bf(float x) {
    unsigned u = __float_as_uint(x);
    unsigned r = 0x7FFFu + ((u >> 16) & 1u);
    return (unsigned short)((u + r) >> 16);
}

#define GLD16(g, l) __builtin_amdgcn_global_load_lds( \
    (const __attribute__((address_space(1))) void*)(g), \
    (__attribute__((address_space(3))) void*)(l), 16, 0, 0)

// -------- maxpool 2x2 (+ init minmax) --------
__global__ void k_maxpool(const float* __restrict__ act, float* __restrict__ ws) {
    int t = threadIdx.x;
    if (blockIdx.x == 0) {
        if (t == 0) ((int*)(ws + WS_MINMAX))[0] = 0x7F800000;
        if (t == 1) ((int*)(ws + WS_MINMAX))[1] = 0;
    }
    int idx = blockIdx.x * 256 + t;
    if (idx >= CCH * 49) return;
    int c = idx / 49, r = idx % 49, y = r / 7, x = r % 7;
    const float* a = act + c * 196 + (2 * y) * 14 + 2 * x;
    float m = fmaxf(fmaxf(a[0], a[1]), fmaxf(a[14], a[15]));
    ws[WS_MP + idx] = m;
}

// -------- layer-1 partials, eighth-row blocks (~13 blocks/CU) --------
// block b: j = b>>3, eighth e = b&7 (64 channels). Writes Dt + eighth-sum qs.
__global__ __launch_bounds__(128) void k_phi4(const float* __restrict__ W1,
                                              const float* __restrict__ mp,
                                              float* __restrict__ Dt,
                                              float* __restrict__ qs) {
    __shared__ float buf[3136];   // 12.25KB products
    int b = blockIdx.x;           // 0..32767
    int j = b >> 3, e = b & 7;
    int t = threadIdx.x;
    const float4* src = (const float4*)(W1 + (size_t)j * F1 + e * 3136);
    const float4* msc = (const float4*)(mp + e * 3136);
    for (int n = t; n < 784; n += 128) {
        float4 w = src[n], m = msc[n];
        float4 p;
        p.x = w.x * m.x; p.y = w.y * m.y; p.z = w.z * m.z; p.w = w.w * m.w;
        *(float4*)&buf[n * 4] = p;
    }
    __syncthreads();
    if (t < 64) {
        const float* bb = buf + t * 49;   // stride 49: 2-way alias only (free)
        float s = 0.f;
        #pragma unroll
        for (int k = 0; k < 49; ++k) s += bb[k];
        Dt[(size_t)j * CCH + e * 64 + t] = s;
        float v = s;
        for (int off = 32; off > 0; off >>= 1) v += __shfl_down(v, off, 64);
        if (t == 0) qs[b] = v;
    }
}

// -------- h1pre from eighth sums --------
__global__ void k_h1b(const float* __restrict__ qs, const float* __restrict__ b1,
                      float* __restrict__ h1pre, float* __restrict__ h1) {
    int j = blockIdx.x * 256 + threadIdx.x;
    if (j < FC) {
        const float* g = qs + j * 8;
        float v = b1[j] + (((g[0] + g[1]) + (g[2] + g[3])) + ((g[4] + g[5]) + (g[6] + g[7])));
        h1pre[j] = v; h1[j] = fmaxf(v, 0.f);
    }
}

// -------- K=4096 GEMV (vectorized) --------
template <bool RELU>
__global__ void k_gemv4096(const float* __restrict__ M, const float* __restrict__ v,
                           const float* __restrict__ bias, float* __restrict__ out) {
    int j = blockIdx.x, t = threadIdx.x;
    const float4* row = (const float4*)(M + (size_t)j * FC);
    const float4* vv = (const float4*)v;
    float s = 0.f;
    #pragma unroll
    for (int q = 0; q < 4; ++q) {
        int n = q * 256 + t;
        float4 w = row[n], x = vv[n];
        s += w.x * x.x + w.y * x.y + w.z * x.z + w.w * x.w;
    }
    __shared__ float red[256];
    red[t] = s; __syncthreads();
    if (t < 128) red[t] += red[t + 128]; __syncthreads();
    if (t < 64)  red[t] += red[t + 64];  __syncthreads();
    if (t < 64) {
        float x = red[t];
        for (int off = 32; off > 0; off >>= 1) x += __shfl_down(x, off, 64);
        if (t == 0) { float r = bias[j] + x; out[j] = RELU ? fmaxf(r, 0.f) : r; }
    }
}

// -------- argmax over logits --------
__global__ void k_argmax(const float* __restrict__ logits, float* __restrict__ clsbase,
                         float* __restrict__ dout_cls) {
    int t = threadIdx.x;
    float best = -INFINITY; int bi = NCLS;
    for (int n = t; n < NCLS; n += 256) {
        float v = logits[n];
        if (v > best || (v == best && n < bi)) { best = v; bi = n; }
    }
    __shared__ float bv[256]; __shared__ int bidx[256];
    bv[t] = best; bidx[t] = bi; __syncthreads();
    for (int o = 128; o > 0; o >>= 1) {
        if (t < o) {
            float v2 = bv[t + o]; int i2 = bidx[t + o];
            if (v2 > bv[t] || (v2 == bv[t] && i2 < bidx[t])) { bv[t] = v2; bidx[t] = i2; }
        }
        __syncthreads();
    }
    if (t == 0) { clsbase[0] = (float)bidx[0]; clsbase[1] = bv[0]; *dout_cls = (float)bidx[0]; }
}

// -------- A[i][k] = relu(h1pre[k] - Dt[k][i]) in bf16, [512][4096] --------
__global__ __launch_bounds__(256) void k_abuild(const float* __restrict__ Dt,
                                                const float* __restrict__ h1pre,
                                                unsigned short* __restrict__ A) {
    __shared__ unsigned short tile[64][72];
    int kt = blockIdx.x, it = blockIdx.y, t = threadIdx.x;
    int k0 = kt * 64, i0 = it * 64;
    #pragma unroll
    for (int q = 0; q < 16; ++q) {
        int kk = q * 4 + (t >> 6);
        int ii = t & 63;
        float v = fmaxf(h1pre[k0 + kk] - Dt[(size_t)(k0 + kk) * CCH + i0 + ii], 0.f);
        tile[kk][ii] = f2bf(v);
    }
    __syncthreads();
    #pragma unroll
    for (int q = 0; q < 4; ++q) {
        int c = q * 256 + t;
        int ii = c >> 4, kc = c & 15;
        ushort4 v;
        v.x = tile[kc * 4 + 0][ii]; v.y = tile[kc * 4 + 1][ii];
        v.z = tile[kc * 4 + 2][ii]; v.w = tile[kc * 4 + 3][ii];
        *(ushort4*)&A[(size_t)(i0 + ii) * FC + k0 + kc * 4] = v;
    }
}

// -------- fused ablation GEMM + base-pass h2 partials (W2 read ONCE total) --------
// grid (128 j-tiles of 32, 4 k-splits) x 512 thr.
// part[ks][m][j] = sum_{k in slice} A[m][k]*W2bf[j][k]
// h2part[ks][j]  = sum_{k in slice} W2f32[j][k]*h1[k]
__global__ __launch_bounds__(512) void k_mfma_all2(
    const unsigned short* __restrict__ A, const float* __restrict__ W2,
    const float* __restrict__ h1, float* __restrict__ part,
    float* __restrict__ h2part) {
    __shared__ char As[65536];    // 512 rows x 8 chunks x 16B
    __shared__ char Bs[4096];     // 32 rows x 8 chunks x 16B
    __shared__ float h1s[KSLICE]; // 4KB
    int nj = blockIdx.x;          // 0..127
    int ks = blockIdx.y;          // 0..3
    int t = threadIdx.x;
    int wid = t >> 6, lane = t & 63, lr = lane & 15, lh = lane >> 4;
    int j0 = nj * TJ;

    {   // stage h1 slice
        float2 v = *(const float2*)(h1 + ks * KSLICE + t * 2);
        *(float2*)&h1s[t * 2] = v;
    }

    int wr = t >> 4;   // 0..31 W2 row in tile
    int wc = t & 15;   // 4-float k-chunk
    const float* wsrc = W2 + (size_t)(j0 + wr) * FC + (size_t)ks * KSLICE + wc * 4;
    char* bdst = Bs + ((size_t)wr * 8 + ((wc >> 1) ^ (wr & 7))) * 16 + (wc & 1) * 8;
    float hacc = 0.f;

    f32x4 acc[4][2];
    #pragma unroll
    for (int f = 0; f < 4; ++f)
        #pragma unroll
        for (int n = 0; n < 2; ++n) acc[f][n] = (f32x4){0.f, 0.f, 0.f, 0.f};

    for (int kst = 0; kst < KSLICE; kst += 64) {
        size_t k0 = (size_t)ks * KSLICE + kst;
        __syncthreads();   // prev MFMA phase done; also publishes h1s on iter 0
        #pragma unroll
        for (int r = 0; r < 8; ++r) {
            int c = t + 512 * r;
            int row = c >> 3, ch = c & 7;
            size_t g = (size_t)row * FC + k0 + (size_t)((ch ^ (row & 7)) * 8);
            GLD16(A + g, As + (size_t)c * 16);
        }
        {
            float4 w = *(const float4*)(wsrc + kst);
            hacc += w.x * h1s[kst + wc * 4] + w.y * h1s[kst + wc * 4 + 1]
                  + w.z * h1s[kst + wc * 4 + 2] + w.w * h1s[kst + wc * 4 + 3];
            ushort4 pk;
            pk.x = f2bf(w.x); pk.y = f2bf(w.y); pk.z = f2bf(w.z); pk.w = f2bf(w.w);
            *(ushort4*)bdst = pk;   // 8B swizzled ds_write
        }
        __syncthreads();   // drains vmcnt (gld_lds) + lgkm (ds_write)
        #pragma unroll
        for (int kf = 0; kf < 2; ++kf) {
            bfrag bfr[2];
            #pragma unroll
            for (int n = 0; n < 2; ++n) {
                int brow = n * 16 + lr;
                bfr[n] = *(const bfrag*)(Bs + ((size_t)brow * 8 + ((kf * 4 + lh) ^ (brow & 7))) * 16);
            }
            #pragma unroll
            for (int f = 0; f < 4; ++f) {
                int arow = wid * 64 + f * 16 + lr;
                bfrag af = *(const bfrag*)(As + ((size_t)arow * 8 + ((kf * 4 + lh) ^ (arow & 7))) * 16);
                #pragma unroll
                for (int n = 0; n < 2; ++n)
                    acc[f][n] = __builtin_amdgcn_mfma_f32_16x16x32_bf16(af, bfr[n], acc[f][n], 0, 0, 0);
            }
        }
    }

    // h2 partial: reduce across the 16 lanes sharing row wr (dependency cone stays in-group)
    for (int off = 8; off > 0; off >>= 1) hacc += __shfl_down(hacc, off, 64);
    if (wc == 0) h2part[ks * FC + j0 + wr] = hacc;

    float* base = part + (size_t)ks * PSTRIDE;
    #pragma unroll
    for (int f = 0; f < 4; ++f)
        #pragma unroll
        for (int n = 0; n < 2; ++n)
            #pragma unroll
            for (int r = 0; r < 4; ++r) {
                int row = wid * 64 + f * 16 + lh * 4 + r;
                base[(size_t)row * FC + j0 + n * 16 + lr] = acc[f][n][r];
            }
}

// -------- h2 = relu(b2 + sum of 4 k-partials) --------
__global__ void k_h2sum(const float* __restrict__ h2part, const float* __restrict__ b2,
                        float* __restrict__ h2) {
    int j = blockIdx.x * 256 + threadIdx.x;
    if (j < FC) {
        float v = b2[j] + ((h2part[j] + h2part[FC + j]) + (h2part[2 * FC + j] + h2part[3 * FC + j]));
        h2[j] = fmaxf(v, 0.f);
    }
}

// -------- per-ablation class logit from k-partials + alpha --------
__global__ __launch_bounds__(256) void k_alpha(
    const float* __restrict__ part, const float* __restrict__ b2,
    const float* __restrict__ W3, const float* __restrict__ b3,
    const float* __restrict__ clsbase, float* __restrict__ alpha) {
    int i = blockIdx.x, t = threadIdx.x;
    int cls = (int)clsbase[0]; float base = clsbase[1];
    const float* w3r = W3 + (size_t)cls * FC;
    const float* p0 = part + (size_t)i * FC;
    float s = 0.f;
    for (int j = t; j < FC; j += 256) {
        float v = ((p0[j] + p0[j + PSTRIDE]) + (p0[j + 2 * PSTRIDE] + p0[j + 3 * PSTRIDE]))
                  + b2[j];
        s += fmaxf(v, 0.f) * w3r[j];
    }
    __shared__ float red[256];
    red[t] = s; __syncthreads();
    if (t < 128) red[t] += red[t + 128]; __syncthreads();
    if (t < 64)  red[t] += red[t + 64];  __syncthreads();
    if (t < 64) {
        float x = red[t];
        for (int off = 32; off > 0; off >>= 1) x += __shfl_down(x, off, 64);
        if (t == 0) {
            float logit = x + b3[cls];
            alpha[i] = (base - logit) / base;
        }
    }
}

// -------- weighted 14x14 map from alpha --------
__global__ void k_weighted2(const float* __restrict__ alpha, const float* __restrict__ act,
                            float* __restrict__ weighted) {
    __shared__ float sA[CCH];
    int t = threadIdx.x;
    for (int i = t; i < CCH; i += 256) sA[i] = alpha[i];
    __syncthreads();
    for (int p = t; p < 196; p += 256) {
        float s = 0.f;
        for (int i = 0; i < CCH; ++i) s = fmaf(sA[i], act[i * 196 + p], s);
        weighted[p] = s;
    }
}

// ======== fallback fp32 path (ws too small) ========
__global__ __launch_bounds__(256) void k_gemm_abl(
    const float* __restrict__ Dt, const float* __restrict__ h1pre,
    const float* __restrict__ W2, const float* __restrict__ b2,
    const float* __restrict__ W3, const float* __restrict__ clsbase,
    float* __restrict__ logit_part) {
    int mi = blockIdx.x, nj = blockIdx.y, t = threadIdx.x;
    int tx = t & 15, ty = t >> 4;
    int i0 = mi * 64, j0 = nj * 64;
    __shared__ float As2[16][64];
    __shared__ float Bs2[16][65];
    float acc[4][4] = {};
    for (int k0 = 0; k0 < FC; k0 += 16) {
        #pragma unroll
        for (int r = 0; r < 4; ++r) {
            int e = t + 256 * r; int kk = e >> 6, ii = e & 63;
            As2[kk][ii] = fmaxf(h1pre[k0 + kk] - Dt[(size_t)(k0 + kk) * CCH + i0 + ii], 0.f);
        }
        {
            int jj = t >> 2, kks = (t & 3) * 4;
            const float4 wv = *(const float4*)(W2 + (size_t)(j0 + jj) * FC + k0 + kks);
            Bs2[kks + 0][jj] = wv.x; Bs2[kks + 1][jj] = wv.y;
            Bs2[kks + 2][jj] = wv.z; Bs2[kks + 3][jj] = wv.w;
        }
        __syncthreads();
        #pragma unroll
        for (int kk = 0; kk < 16; ++kk) {
            float4 a4 = *(const float4*)&As2[kk][tx * 4];
            float av[4] = {a4.x, a4.y, a4.z, a4.w};
            float bv[4] = {Bs2[kk][ty * 4 + 0], Bs2[kk][ty * 4 + 1],
                           Bs2[kk][ty * 4 + 2], Bs2[kk][ty * 4 + 3]};
            #pragma unroll
            for (int a = 0; a < 4; ++a)
                #pragma unroll
                for (int b = 0; b < 4; ++b)
                    acc[a][b] = fmaf(av[a], bv[b], acc[a][b]);
        }
        __syncthreads();
    }
    int cls = (int)clsbase[0];
    const float* w3r = W3 + (size_t)cls * FC;
    float prt[4] = {0.f, 0.f, 0.f, 0.f};
    #pragma unroll
    for (int b = 0; b < 4; ++b) {
        int j2 = j0 + ty * 4 + b;
        float bb = b2[j2], w3 = w3r[j2];
        #pragma unroll
        for (int a = 0; a < 4; ++a) prt[a] = fmaf(fmaxf(acc[a][b] + bb, 0.f), w3, prt[a]);
    }
    __shared__ float red2[16][68];
    #pragma unroll
    for (int a = 0; a < 4; ++a) red2[ty][tx * 4 + a] = prt[a];
    __syncthreads();
    if (t < 64) {
        float s = 0.f;
        #pragma unroll
        for (int q = 0; q < 16; ++q) s += red2[q][t];
        logit_part[nj * CCH + i0 + t] = s;
    }
}

__global__ void k_alpha_fb(const float* __restrict__ logit_part, const float* __restrict__ b3,
                           const float* __restrict__ clsbase, float* __restrict__ alpha) {
    int t = blockIdx.x * 256 + threadIdx.x;
    if (t >= CCH) return;
    int cls = (int)clsbase[0]; float base = clsbase[1];
    float s = 0.f;
    for (int q = 0; q < 64; ++q) s += logit_part[q * CCH + t];
    alpha[t] = (base - (s + b3[cls])) / base;
}

// -------- bilinear 14->224 + relu + min/max --------
__global__ void k_resize(const float* __restrict__ weighted, float* __restrict__ out,
                         int* __restrict__ minmax) {
    __shared__ float sW[196];
    int t = threadIdx.x;
    if (t < 196) sW[t] = weighted[t];
    __syncthreads();
    int pix = blockIdx.x * 256 + t;
    int y = pix / OW, x = pix % OW;
    float uy = (y + 0.5f) * 0.0625f - 0.5f;
    float ux = (x + 0.5f) * 0.0625f - 0.5f;
    float y0f = floorf(uy), x0f = floorf(ux);
    float fy = uy - y0f, fx = ux - x0f;
    int y0 = (int)y0f, x0 = (int)x0f;
    int y0c = min(max(y0, 0), 13), y1c = min(max(y0 + 1, 0), 13);
    int x0c = min(max(x0, 0), 13), x1c = min(max(x0 + 1, 0), 13);
    float v00 = sW[y0c * 14 + x0c], v01 = sW[y0c * 14 + x1c];
    float v10 = sW[y1c * 14 + x0c], v11 = sW[y1c * 14 + x1c];
    float v0 = v00 + (v01 - v00) * fx;
    float v1 = v10 + (v11 - v10) * fx;
    float v = v0 + (v1 - v0) * fy;
    float f = fmaxf(v, 0.f);
    out[pix] = f;
    __shared__ float rmn[256], rmx[256];
    rmn[t] = f; rmx[t] = f; __syncthreads();
    for (int o = 128; o > 0; o >>= 1) {
        if (t < o) { rmn[t] = fminf(rmn[t], rmn[t + o]); rmx[t] = fmaxf(rmx[t], rmx[t + o]); }
        __syncthreads();
    }
    if (t == 0) {
        atomicMin(&minmax[0], __float_as_int(rmn[0]));
        atomicMax(&minmax[1], __float_as_int(rmx[0]));
    }
}

__global__ void k_norm(float* __restrict__ out, const int* __restrict__ minmax) {
    float mn = __int_as_float(minmax[0]);
    float mx = __int_as_float(minmax[1]);
    int pix = blockIdx.x * 256 + threadIdx.x;
    if (mx != mn) out[pix] = (out[pix] - mn) / (mx - mn);
}

extern "C" void kernel_launch(void* const* d_in, const int* in_sizes, int n_in,
                              void* d_out, int out_size, void* d_ws, size_t ws_size,
                              hipStream_t stream) {
    const float* act = (const float*)d_in[0];
    const float* W1  = (const float*)d_in[1];
    const float* b1  = (const float*)d_in[2];
    const float* W2  = (const float*)d_in[3];
    const float* b2  = (const float*)d_in[4];
    const float* W3  = (const float*)d_in[5];
    const float* b3  = (const float*)d_in[6];
    float* out = (float*)d_out;
    float* ws = (float*)d_ws;
    const bool fast = (ws_size >= WS_NEED_BYTES);

    k_maxpool<<<98, 256, 0, stream>>>(act, ws);
    k_phi4<<<32768, 128, 0, stream>>>(W1, ws + WS_MP, ws + WS_DT, ws + WS_QS);
    k_h1b<<<16, 256, 0, stream>>>(ws + WS_QS, b1, ws + WS_H1PRE, ws + WS_H1);
    if (fast) {
        k_abuild<<<dim3(64, 8), 256, 0, stream>>>(ws + WS_DT, ws + WS_H1PRE,
                                                  (unsigned short*)(ws + WS_A));
        k_mfma_all2<<<dim3(128, KSPLIT), 512, 0, stream>>>(
            (const unsigned short*)(ws + WS_A), W2, ws + WS_H1,
            ws + WS_PART, ws + WS_H2PART);
        k_h2sum<<<16, 256, 0, stream>>>(ws + WS_H2PART, b2, ws + WS_H2);
        k_gemv4096<false><<<1000, 256, 0, stream>>>(W3, ws + WS_H2, b3, ws + WS_LOGITS);
        k_argmax<<<1, 256, 0, stream>>>(ws + WS_LOGITS, ws + WS_CLSBASE, out + 50176);
        k_alpha<<<CCH, 256, 0, stream>>>(ws + WS_PART, b2, W3, b3,
                                         ws + WS_CLSBASE, ws + WS_ALPHA);
    } else {
        k_gemv4096<true><<<4096, 256, 0, stream>>>(W2, ws + WS_H1, b2, ws + WS_H2);
        k_gemv4096<false><<<1000, 256, 0, stream>>>(W3, ws + WS_H2, b3, ws + WS_LOGITS);
        k_argmax<<<1, 256, 0, stream>>>(ws + WS_LOGITS, ws + WS_CLSBASE, out + 50176);
        k_gemm_abl<<<dim3(8, 64), 256, 0, stream>>>(ws + WS_DT, ws + WS_H1PRE, W2, b2, W3,
                                                    ws + WS_CLSBASE, ws + WS_LOGPART);
        k_alpha_fb<<<2, 256, 0, stream>>>(ws + WS_LOGPART, b3, ws + WS_CLSBASE,
                                          ws + WS_ALPHA);
    }
    k_weighted2<<<1, 256, 0, stream>>>(ws + WS_ALPHA, act, ws + WS_WEIGHTED);
    k_resize<<<196, 256, 0, stream>>>(ws + WS_WEIGHTED, out, (int*)(ws + WS_MINMAX));
    k_norm<<<196, 256, 0, stream>>>(out, (const int*)(ws + WS_MINMAX));
}